// Round 4
// baseline (506.499 us; speedup 1.0000x reference)
//
#include <hip/hip_runtime.h>
#include <hip/hip_bf16.h>
#include <cstdint>

#define E_ 32
#define H_ 1024
#define I_ 512
#define G_ 8
#define NSH_ 2
#define SCALE_ 2.5f
#define NROUTED (E_ * I_)            // 16384
#define PADCAP (16384 + E_ * 128)    // 20480, pad-to-128

typedef unsigned short u16;
using bf16x8_t = __attribute__((ext_vector_type(8))) __bf16;
using f32x4_t  = __attribute__((ext_vector_type(4))) float;

__device__ __forceinline__ u16 f2bf(float x) {
  union { float f; uint32_t u; } v; v.f = x;
  uint32_t u = v.u;
  uint32_t r = (u + 0x7fffu + ((u >> 16) & 1u)) >> 16;
  return (u16)r;
}
__device__ __forceinline__ float bf2f(u16 x) {
  union { uint32_t u; float f; } v; v.u = ((uint32_t)x) << 16; return v.f;
}

__device__ __forceinline__ void load_lds16(const void* g, void* l) {
  __builtin_amdgcn_global_load_lds(
      (const __attribute__((address_space(1))) unsigned int*)g,
      (__attribute__((address_space(3))) unsigned int*)l,
      16, 0, 0);
}

// ---------------- f32 -> bf16 conversion (hs only) ----------------
__global__ void cvt_kernel(const float* __restrict__ src, u16* __restrict__ dst, long n4) {
  long i = (long)blockIdx.x * blockDim.x + threadIdx.x;
  if (i >= n4) return;
  float4 v = ((const float4*)src)[i];
  ushort4 o;
  o.x = f2bf(v.x); o.y = f2bf(v.y); o.z = f2bf(v.z); o.w = f2bf(v.w);
  ((ushort4*)dst)[i] = o;
}

// ---------------- init ----------------
__global__ void init_kernel(int* __restrict__ counts, int* __restrict__ cursor,
                            int* __restrict__ tok_list, float* __restrict__ wt_list) {
  int i = blockIdx.x * blockDim.x + threadIdx.x;
  if (i < PADCAP) { tok_list[i] = 0; wt_list[i] = 0.f; }
  if (i < E_) { counts[i] = 0; cursor[i] = 0; }
}

// ---------------- router a: gw [E][H] -> gwT [H][E] ----------------
__global__ void gwt_kernel(const float* __restrict__ gw, float* __restrict__ gwT) {
  int i = blockIdx.x * blockDim.x + threadIdx.x;
  if (i >= H_ * E_) return;
  int k = i >> 5, e = i & 31;
  gwT[i] = gw[(long)e * H_ + k];
}

// ---------------- router b: logits = h @ gwT (f32 exact) ----------
__global__ __launch_bounds__(256) void logits_kernel(
    const float* __restrict__ h, const float* __restrict__ gwT,
    float* __restrict__ logits) {
  __shared__ float sh[8][H_];
  const int tid = threadIdx.x;
  const int t0 = blockIdx.x * 8;
  #pragma unroll
  for (int c = tid; c < 8 * H_ / 4; c += 256) {
    int row = c / (H_ / 4), col = c % (H_ / 4);
    ((float4*)sh[row])[col] = ((const float4*)(h + (size_t)(t0 + row) * H_))[col];
  }
  __syncthreads();
  const int w = tid >> 6, l = tid & 63;
  const int e = l & 31, tl = w * 2 + (l >> 5);
  const float* hp = sh[tl];
  const float* wp = gwT + e;
  float acc = 0.f;
  #pragma unroll 8
  for (int k = 0; k < H_; ++k) acc += hp[k] * wp[(size_t)k * E_];
  logits[(size_t)(t0 + tl) * E_ + e] = acc;
}

// ---------------- router c: top-k (1 thread / token) ----------------
__global__ __launch_bounds__(256) void topk_kernel(
    const float* __restrict__ logits, const float* __restrict__ gb,
    int* __restrict__ idx8, float* __restrict__ wt8, int* __restrict__ counts) {
  __shared__ float s_sc[256][33];
  const int lt = threadIdx.x;
  const int t = blockIdx.x * 256 + lt;
  float sc[E_];
  #pragma unroll
  for (int e = 0; e < E_; ++e) {
    float lg = logits[(size_t)t * E_ + e];
    float sig = 1.f / (1.f + __expf(-lg));
    s_sc[lt][e] = sig;
    sc[e] = sig + gb[e];
  }
  float gs[G_];
  #pragma unroll
  for (int g = 0; g < G_; ++g) {
    float a = sc[g * 4], b = sc[g * 4 + 1], c = sc[g * 4 + 2], d = sc[g * 4 + 3];
    float hi1 = fmaxf(a, b), lo1 = fminf(a, b);
    float hi2 = fmaxf(c, d), lo2 = fminf(c, d);
    float m1 = fmaxf(hi1, hi2);
    float m2 = (hi1 >= hi2) ? fmaxf(lo1, hi2) : fmaxf(lo2, hi1);
    gs[g] = m1 + m2;
  }
  unsigned gm = 0;
  #pragma unroll
  for (int r = 0; r < 4; ++r) {
    float bv = -1e30f; int bi = 0;
    #pragma unroll
    for (int g = 0; g < G_; ++g)
      if (!(gm & (1u << g)) && gs[g] > bv) { bv = gs[g]; bi = g; }
    gm |= 1u << bi;
  }
  float msk[E_];
  #pragma unroll
  for (int e = 0; e < E_; ++e)
    msk[e] = ((gm >> (e >> 2)) & 1u) ? sc[e] : 0.f;
  unsigned um = 0; float wsum = 0.f;
  int idxs[8]; float wts[8];
  #pragma unroll
  for (int r = 0; r < 8; ++r) {
    float bv = -1e30f; int bi = 0;
    #pragma unroll
    for (int e = 0; e < E_; ++e)
      if (!(um & (1u << e)) && msk[e] > bv) { bv = msk[e]; bi = e; }
    um |= 1u << bi;
    idxs[r] = bi;
    float wv = s_sc[lt][bi];
    wts[r] = wv; wsum += wv;
  }
  float inv = SCALE_ / (wsum + 1e-20f);
  #pragma unroll
  for (int r = 0; r < 8; ++r) {
    idx8[(size_t)t * 8 + r] = idxs[r];
    wt8[(size_t)t * 8 + r] = wts[r] * inv;
    atomicAdd(&counts[idxs[r]], 1);
  }
}

// ---------------- scan (pad to 128) ----------------
__global__ void scan_kernel(const int* __restrict__ counts, int* __restrict__ offs) {
  if (threadIdx.x == 0 && blockIdx.x == 0) {
    int run = 0;
    for (int e = 0; e < E_; ++e) {
      offs[e] = run;
      run += ((counts[e] + 127) >> 7) << 7;
    }
    offs[E_] = run;
  }
}

// ---------------- fill ----------------
__global__ void fill_kernel(const int* __restrict__ idx8, const float* __restrict__ wt8,
                            const int* __restrict__ offs, int* __restrict__ cursor,
                            int* __restrict__ tok_list, float* __restrict__ wt_list,
                            int* __restrict__ pair_pos, int npair) {
  int i = blockIdx.x * blockDim.x + threadIdx.x;
  if (i >= npair) return;
  int e = idx8[i];
  int p = atomicAdd(&cursor[e], 1);
  int slot = offs[e] + p;
  tok_list[slot] = i >> 3;
  wt_list[slot] = wt8[i];
  pair_pos[i] = slot;
}

// ---------------- phase 1: gathered dual GEMM, dbuf 2-phase ----------------
// 512 thr = 8 waves (2x4). Tile 128 tok x 128 cols. Wave: FM=4, FN=2, dual acc.
// B (weights) read as f32 directly, reg-staged -> bf16 -> LDS (T14 split).
__global__ __launch_bounds__(512, 2) void p1_kernel(
    const u16* __restrict__ hbf,
    const float* __restrict__ wg, const float* __restrict__ wu,
    const float* __restrict__ shg, const float* __restrict__ shu,
    const int* __restrict__ counts, const int* __restrict__ offs,
    const int* __restrict__ tok_list, const float* __restrict__ wt_list,
    u16* __restrict__ gu,          // [PADCAP][512]
    u16* __restrict__ gu_sh,       // [T][1024]
    int T) {
  const int z = blockIdx.z, tt = blockIdx.y, nb = blockIdx.x;
  const bool sh_e = (z == E_);
  if (!sh_e && nb >= 4) return;
  const int cnt = sh_e ? T : counts[z];
  if (tt * 128 >= cnt) return;
  const int off = sh_e ? 0 : offs[z];

  __shared__ u16 lsA[2][128 * 64];
  __shared__ u16 lsB0[2][128 * 64];
  __shared__ u16 lsB1[2][128 * 64];
  __shared__ int s_tok[128];
  __shared__ float s_wt[128];

  const int tid = threadIdx.x;
  if (tid < 128) {
    if (sh_e) { s_tok[tid] = tt * 128 + tid; s_wt[tid] = 1.0f; }
    else {
      int slot = off + tt * 128 + tid;
      s_tok[tid] = tok_list[slot];
      s_wt[tid] = wt_list[slot];
    }
  }
  __syncthreads();

  const float* Bg = sh_e ? (shg + (size_t)(nb * 128) * H_)
                         : (wg + ((size_t)z * I_ + nb * 128) * H_);
  const float* Bu = sh_e ? (shu + (size_t)(nb * 128) * H_)
                         : (wu + ((size_t)z * I_ + nb * 128) * H_);

  const int w = tid >> 6, l = tid & 63;
  const int wr = w >> 2, wc = w & 3;
  const int lr = l & 15, lh = l >> 4;

  f32x4_t acc0[4][2], acc1[4][2];
  #pragma unroll
  for (int m = 0; m < 4; ++m)
    #pragma unroll
    for (int n = 0; n < 2; ++n) {
      acc0[m][n] = (f32x4_t){0.f, 0.f, 0.f, 0.f};
      acc1[m][n] = (f32x4_t){0.f, 0.f, 0.f, 0.f};
    }

  float4 rB0[4], rB1[4];

  auto stageA = [&](u16* dst, int k0) {
    #pragma unroll
    for (int i = 0; i < 2; ++i) {
      int c = tid + 512 * i;
      int row = c >> 3, cb = c & 7;
      load_lds16(hbf + (size_t)s_tok[row] * H_ + k0 + cb * 8, (char*)dst + c * 16);
    }
  };
  auto loadB = [&](int k0) {
    #pragma unroll
    for (int i = 0; i < 4; ++i) {
      int c = tid + 512 * i;
      int row = c >> 4, cb = c & 15;
      rB0[i] = *(const float4*)(Bg + (size_t)row * H_ + k0 + cb * 4);
      rB1[i] = *(const float4*)(Bu + (size_t)row * H_ + k0 + cb * 4);
    }
  };
  auto writeB = [&](u16* d0, u16* d1) {
    #pragma unroll
    for (int i = 0; i < 4; ++i) {
      int c = tid + 512 * i;
      int row = c >> 4, cb = c & 15;
      ushort4 o0, o1;
      o0.x = f2bf(rB0[i].x); o0.y = f2bf(rB0[i].y); o0.z = f2bf(rB0[i].z); o0.w = f2bf(rB0[i].w);
      o1.x = f2bf(rB1[i].x); o1.y = f2bf(rB1[i].y); o1.z = f2bf(rB1[i].z); o1.w = f2bf(rB1[i].w);
      *(ushort4*)(d0 + row * 64 + cb * 4) = o0;
      *(ushort4*)(d1 + row * 64 + cb * 4) = o1;
    }
  };
  auto compute = [&](const u16* a, const u16* b0, const u16* b1) {
    #pragma unroll
    for (int kk = 0; kk < 64; kk += 32) {
      bf16x8_t af[4], b0f[2], b1f[2];
      #pragma unroll
      for (int m = 0; m < 4; ++m)
        af[m] = *(const bf16x8_t*)(a + (wr * 64 + m * 16 + lr) * 64 + kk + lh * 8);
      #pragma unroll
      for (int n = 0; n < 2; ++n) {
        b0f[n] = *(const bf16x8_t*)(b0 + (wc * 32 + n * 16 + lr) * 64 + kk + lh * 8);
        b1f[n] = *(const bf16x8_t*)(b1 + (wc * 32 + n * 16 + lr) * 64 + kk + lh * 8);
      }
      #pragma unroll
      for (int m = 0; m < 4; ++m)
        #pragma unroll
        for (int n = 0; n < 2; ++n) {
          acc0[m][n] = __builtin_amdgcn_mfma_f32_16x16x32_bf16(af[m], b0f[n], acc0[m][n], 0, 0, 0);
          acc1[m][n] = __builtin_amdgcn_mfma_f32_16x16x32_bf16(af[m], b1f[n], acc1[m][n], 0, 0, 0);
        }
    }
  };

  // prologue
  loadB(0);
  stageA(lsA[0], 0);
  writeB(lsB0[0], lsB1[0]);
  __syncthreads();
  int cur = 0;
  for (int s = 0; s < 16; ++s) {
    if (s < 15) { loadB((s + 1) * 64); stageA(lsA[cur ^ 1], (s + 1) * 64); }
    compute(lsA[cur], lsB0[cur], lsB1[cur]);
    if (s < 15) writeB(lsB0[cur ^ 1], lsB1[cur ^ 1]);
    __syncthreads();
    cur ^= 1;
  }

  const int ldo = sh_e ? (I_ * NSH_) : I_;
  u16* outp = sh_e ? (gu_sh + (size_t)(tt * 128) * ldo + nb * 128)
                   : (gu + (size_t)(off + tt * 128) * ldo + nb * 128);
  #pragma unroll
  for (int m = 0; m < 4; ++m) {
    #pragma unroll
    for (int n = 0; n < 2; ++n) {
      int col = wc * 32 + n * 16 + lr;
      #pragma unroll
      for (int j = 0; j < 4; ++j) {
        int trow = wr * 64 + m * 16 + lh * 4 + j;
        float gv = acc0[m][n][j], uv = acc1[m][n][j];
        float sv = gv / (1.f + __expf(-gv));
        outp[(size_t)trow * ldo + col] = f2bf(sv * uv * s_wt[trow]);
      }
    }
  }
}

// ---------------- phase 2: gathered GEMM (down), dbuf 2-phase ----------------
// 512 thr = 8 waves. Tile 128 pairs x 128 H-cols. K=512 routed / 1024 shared.
__global__ __launch_bounds__(512, 2) void p2_kernel(
    const u16* __restrict__ gu, const u16* __restrict__ gu_sh,
    const float* __restrict__ wd,   // [E][H][I] f32
    const float* __restrict__ shd,  // [H][2I] f32
    const int* __restrict__ counts, const int* __restrict__ offs,
    u16* __restrict__ part,         // [PADCAP][H]
    u16* __restrict__ part_sh,      // [T][H]
    int T) {
  const int z = blockIdx.z, tt = blockIdx.y, nb = blockIdx.x;
  const bool sh_e = (z == E_);
  const int cnt = sh_e ? T : counts[z];
  if (tt * 128 >= cnt) return;

  __shared__ u16 lsA[2][128 * 64];
  __shared__ u16 lsB[2][128 * 64];

  const int tid = threadIdx.x;
  const int w = tid >> 6, l = tid & 63;
  const int wr = w >> 2, wc = w & 3;
  const int lr = l & 15, lh = l >> 4;

  const int K = sh_e ? (I_ * NSH_) : I_;
  const int NT = K / 64;
  const u16* Ab = sh_e ? (gu_sh + (size_t)(tt * 128) * K)
                       : (gu + (size_t)(offs[z] + tt * 128) * K);
  const float* Bb = sh_e ? (shd + (size_t)(nb * 128) * K)
                         : (wd + (size_t)z * H_ * I_ + (size_t)(nb * 128) * K);
  u16* outp = sh_e ? (part_sh + (size_t)(tt * 128) * H_ + nb * 128)
                   : (part + (size_t)(offs[z] + tt * 128) * H_ + nb * 128);

  f32x4_t acc[4][2];
  #pragma unroll
  for (int m = 0; m < 4; ++m)
    #pragma unroll
    for (int n = 0; n < 2; ++n) acc[m][n] = (f32x4_t){0.f, 0.f, 0.f, 0.f};

  float4 rB[4];
  auto stageA = [&](u16* dst, int k0) {
    #pragma unroll
    for (int i = 0; i < 2; ++i) {
      int c = tid + 512 * i;
      int row = c >> 3, cb = c & 7;
      load_lds16(Ab + (size_t)row * K + k0 + cb * 8, (char*)dst + c * 16);
    }
  };
  auto loadB = [&](int k0) {
    #pragma unroll
    for (int i = 0; i < 4; ++i) {
      int c = tid + 512 * i;
      int row = c >> 4, cb = c & 15;
      rB[i] = *(const float4*)(Bb + (size_t)row * K + k0 + cb * 4);
    }
  };
  auto writeB = [&](u16* d) {
    #pragma unroll
    for (int i = 0; i < 4; ++i) {
      int c = tid + 512 * i;
      int row = c >> 4, cb = c & 15;
      ushort4 o;
      o.x = f2bf(rB[i].x); o.y = f2bf(rB[i].y); o.z = f2bf(rB[i].z); o.w = f2bf(rB[i].w);
      *(ushort4*)(d + row * 64 + cb * 4) = o;
    }
  };
  auto compute = [&](const u16* a, const u16* b) {
    #pragma unroll
    for (int kk = 0; kk < 64; kk += 32) {
      bf16x8_t af[4], bf[2];
      #pragma unroll
      for (int m = 0; m < 4; ++m)
        af[m] = *(const bf16x8_t*)(a + (wr * 64 + m * 16 + lr) * 64 + kk + lh * 8);
      #pragma unroll
      for (int n = 0; n < 2; ++n)
        bf[n] = *(const bf16x8_t*)(b + (wc * 32 + n * 16 + lr) * 64 + kk + lh * 8);
      #pragma unroll
      for (int m = 0; m < 4; ++m)
        #pragma unroll
        for (int n = 0; n < 2; ++n)
          acc[m][n] = __builtin_amdgcn_mfma_f32_16x16x32_bf16(af[m], bf[n], acc[m][n], 0, 0, 0);
    }
  };

  loadB(0);
  stageA(lsA[0], 0);
  writeB(lsB[0]);
  __syncthreads();
  int cur = 0;
  for (int s = 0; s < NT; ++s) {
    if (s < NT - 1) { loadB((s + 1) * 64); stageA(lsA[cur ^ 1], (s + 1) * 64); }
    compute(lsA[cur], lsB[cur]);
    if (s < NT - 1) writeB(lsB[cur ^ 1]);
    __syncthreads();
    cur ^= 1;
  }

  #pragma unroll
  for (int m = 0; m < 4; ++m) {
    #pragma unroll
    for (int n = 0; n < 2; ++n) {
      int col = wc * 32 + n * 16 + lr;
      #pragma unroll
      for (int j = 0; j < 4; ++j) {
        int trow = wr * 64 + m * 16 + lh * 4 + j;
        outp[(size_t)trow * H_ + col] = f2bf(acc[m][n][j]);
      }
    }
  }
}

// ---------------- combine ----------------
__global__ void combine_kernel(const u16* __restrict__ part, const u16* __restrict__ part_sh,
                               const int* __restrict__ pair_pos, float* __restrict__ out) {
  int t = blockIdx.x;
  int h = threadIdx.x * 4;
  int pp[8];
  #pragma unroll
  for (int s = 0; s < 8; ++s) pp[s] = pair_pos[(long)t * 8 + s];
  ushort4 v = *(const ushort4*)(part_sh + (size_t)t * H_ + h);
  float a0 = bf2f(v.x), a1 = bf2f(v.y), a2 = bf2f(v.z), a3 = bf2f(v.w);
  #pragma unroll
  for (int s = 0; s < 8; ++s) {
    ushort4 u = *(const ushort4*)(part + (size_t)pp[s] * H_ + h);
    a0 += bf2f(u.x); a1 += bf2f(u.y); a2 += bf2f(u.z); a3 += bf2f(u.w);
  }
  float4 o = {a0, a1, a2, a3};
  *(float4*)(out + (size_t)t * H_ + h) = o;
}

extern "C" void kernel_launch(void* const* d_in, const int* in_sizes, int n_in,
                              void* d_out, int out_size, void* d_ws, size_t ws_size,
                              hipStream_t stream) {
  const float* hs  = (const float*)d_in[0];
  const float* gw  = (const float*)d_in[1];
  const float* gb  = (const float*)d_in[2];
  const float* wg  = (const float*)d_in[3];
  const float* wu  = (const float*)d_in[4];
  const float* wd  = (const float*)d_in[5];
  const float* shg = (const float*)d_in[6];
  const float* shu = (const float*)d_in[7];
  const float* shd = (const float*)d_in[8];
  float* out = (float*)d_out;

  const int T = in_sizes[0] / H_;  // 2048

  char* ws = (char*)d_ws;
  size_t off = 0;
  auto alloc = [&](size_t bytes) {
    char* p = ws + off;
    off += (bytes + 255) & ~(size_t)255;
    return p;
  };
  int*   counts   = (int*)alloc(E_ * 4);
  int*   cursor   = (int*)alloc(E_ * 4);
  int*   offsv    = (int*)alloc((E_ + 1) * 4);
  int*   idx8     = (int*)alloc((size_t)T * 8 * 4);
  float* wt8      = (float*)alloc((size_t)T * 8 * 4);
  int*   pair_pos = (int*)alloc((size_t)T * 8 * 4);
  int*   tok_list = (int*)alloc(PADCAP * 4);
  float* wt_list  = (float*)alloc(PADCAP * 4);
  float* gwT      = (float*)alloc((size_t)H_ * E_ * 4);
  float* logits   = (float*)alloc((size_t)T * E_ * 4);
  u16* hbf     = (u16*)alloc((size_t)T * H_ * 2);
  u16* gu      = (u16*)alloc((size_t)PADCAP * I_ * 2);
  u16* gu_sh   = (u16*)alloc((size_t)T * I_ * NSH_ * 2);
  u16* part    = (u16*)alloc((size_t)PADCAP * H_ * 2);
  u16* part_sh = (u16*)alloc((size_t)T * H_ * 2);
  if (off > ws_size) return;

  hipLaunchKernelGGL(init_kernel, dim3((PADCAP + 255) / 256), dim3(256), 0, stream,
                     counts, cursor, tok_list, wt_list);

  // router (f32 exact)
  hipLaunchKernelGGL(gwt_kernel, dim3((H_ * E_ + 255) / 256), dim3(256), 0, stream, gw, gwT);
  hipLaunchKernelGGL(logits_kernel, dim3(T / 8), dim3(256), 0, stream, hs, gwT, logits);
  hipLaunchKernelGGL(topk_kernel, dim3(T / 256), dim3(256), 0, stream,
                     logits, gb, idx8, wt8, counts);
  hipLaunchKernelGGL(scan_kernel, dim3(1), dim3(64), 0, stream, counts, offsv);
  hipLaunchKernelGGL(fill_kernel, dim3((T * 8 + 255) / 256), dim3(256), 0, stream,
                     idx8, wt8, offsv, cursor, tok_list, wt_list, pair_pos, T * 8);

  // hs -> bf16 (weights stay f32, converted in-register during staging)
  {
    long n4 = (long)T * H_ / 4;
    hipLaunchKernelGGL(cvt_kernel, dim3((int)((n4 + 255) / 256)), dim3(256), 0, stream,
                       hs, hbf, n4);
  }

  hipLaunchKernelGGL(p1_kernel, dim3(8, T / 128, E_ + 1), dim3(512), 0, stream,
                     hbf, wg, wu, shg, shu, counts, offsv, tok_list, wt_list,
                     gu, gu_sh, T);

  hipLaunchKernelGGL(p2_kernel, dim3(8, T / 128, E_ + 1), dim3(512), 0, stream,
                     gu, gu_sh, wd, shd, counts, offsv, part, part_sh, T);

  hipLaunchKernelGGL(combine_kernel, dim3(T), dim3(256), 0, stream,
                     part, part_sh, pair_pos, out);
}

// Round 5
// 362.260 us; speedup vs baseline: 1.3982x; 1.3982x over previous
//
#include <hip/hip_runtime.h>
#include <hip/hip_bf16.h>
#include <cstdint>

#define E_ 32
#define H_ 1024
#define I_ 512
#define G_ 8
#define NSH_ 2
#define SCALE_ 2.5f
#define NROUTED (E_ * I_)            // 16384
#define PADCAP (16384 + E_ * 64)     // 18432, pad-to-64

typedef unsigned short u16;
using bf16x8_t = __attribute__((ext_vector_type(8))) __bf16;
using f32x4_t  = __attribute__((ext_vector_type(4))) float;

__device__ __forceinline__ u16 f2bf(float x) {
  union { float f; uint32_t u; } v; v.f = x;
  uint32_t u = v.u;
  uint32_t r = (u + 0x7fffu + ((u >> 16) & 1u)) >> 16;
  return (u16)r;
}
__device__ __forceinline__ float bf2f(u16 x) {
  union { uint32_t u; float f; } v; v.u = ((uint32_t)x) << 16; return v.f;
}

__device__ __forceinline__ void load_lds16(const void* g, void* l) {
  __builtin_amdgcn_global_load_lds(
      (const __attribute__((address_space(1))) unsigned int*)g,
      (__attribute__((address_space(3))) unsigned int*)l,
      16, 0, 0);
}

// ---------------- hs f32 -> bf16 ----------------
__global__ void cvt_kernel(const float* __restrict__ src, u16* __restrict__ dst, long n4) {
  long i = (long)blockIdx.x * blockDim.x + threadIdx.x;
  if (i >= n4) return;
  float4 v = ((const float4*)src)[i];
  ushort4 o;
  o.x = f2bf(v.x); o.y = f2bf(v.y); o.z = f2bf(v.z); o.w = f2bf(v.w);
  ((ushort4*)dst)[i] = o;
}

// ---------------- all weights f32 -> bf16, one grid-stride kernel ----------
// dst layout (u16 elems): [wg | wu | wd | shg | shu | shd]
#define W4_WG  4194304L
#define W4_WU  8388608L
#define W4_WD  12582912L
#define W4_SHG 12845056L
#define W4_SHU 13107200L
#define W4_TOT 13369344L
__global__ void cvtw_kernel(const float* __restrict__ wg, const float* __restrict__ wu,
                            const float* __restrict__ wd, const float* __restrict__ shg,
                            const float* __restrict__ shu, const float* __restrict__ shd,
                            u16* __restrict__ dst) {
  long i = (long)blockIdx.x * blockDim.x + threadIdx.x;
  long stride = (long)gridDim.x * blockDim.x;
  for (; i < W4_TOT; i += stride) {
    const float* s; long off;
    if (i < W4_WG)       { s = wg;  off = i; }
    else if (i < W4_WU)  { s = wu;  off = i - W4_WG; }
    else if (i < W4_WD)  { s = wd;  off = i - W4_WU; }
    else if (i < W4_SHG) { s = shg; off = i - W4_WD; }
    else if (i < W4_SHU) { s = shu; off = i - W4_SHG; }
    else                 { s = shd; off = i - W4_SHU; }
    float4 v = ((const float4*)s)[off];
    ushort4 o;
    o.x = f2bf(v.x); o.y = f2bf(v.y); o.z = f2bf(v.z); o.w = f2bf(v.w);
    ((ushort4*)dst)[i] = o;
  }
}

// ---------------- init ----------------
__global__ void init_kernel(int* __restrict__ counts, int* __restrict__ cursor,
                            int* __restrict__ tok_list, float* __restrict__ wt_list) {
  int i = blockIdx.x * blockDim.x + threadIdx.x;
  if (i < PADCAP) { tok_list[i] = 0; wt_list[i] = 0.f; }
  if (i < E_) { counts[i] = 0; cursor[i] = 0; }
}

// ---------------- router a: gw [E][H] -> gwT [H][E] ----------------
__global__ void gwt_kernel(const float* __restrict__ gw, float* __restrict__ gwT) {
  int i = blockIdx.x * blockDim.x + threadIdx.x;
  if (i >= H_ * E_) return;
  int k = i >> 5, e = i & 31;
  gwT[i] = gw[(long)e * H_ + k];
}

// ---------------- router b: logits (f32 exact) ----------
__global__ __launch_bounds__(256) void logits_kernel(
    const float* __restrict__ h, const float* __restrict__ gwT,
    float* __restrict__ logits) {
  __shared__ float sh[8][H_];
  const int tid = threadIdx.x;
  const int t0 = blockIdx.x * 8;
  #pragma unroll
  for (int c = tid; c < 8 * H_ / 4; c += 256) {
    int row = c / (H_ / 4), col = c % (H_ / 4);
    ((float4*)sh[row])[col] = ((const float4*)(h + (size_t)(t0 + row) * H_))[col];
  }
  __syncthreads();
  const int w = tid >> 6, l = tid & 63;
  const int e = l & 31, tl = w * 2 + (l >> 5);
  const float* hp = sh[tl];
  const float* wp = gwT + e;
  float acc = 0.f;
  #pragma unroll 8
  for (int k = 0; k < H_; ++k) acc += hp[k] * wp[(size_t)k * E_];
  logits[(size_t)(t0 + tl) * E_ + e] = acc;
}

// ---------------- router c: top-k (1 thread / token) ----------------
__global__ __launch_bounds__(256) void topk_kernel(
    const float* __restrict__ logits, const float* __restrict__ gb,
    int* __restrict__ idx8, float* __restrict__ wt8, int* __restrict__ counts) {
  __shared__ float s_sc[256][33];
  const int lt = threadIdx.x;
  const int t = blockIdx.x * 256 + lt;
  float sc[E_];
  #pragma unroll
  for (int e = 0; e < E_; ++e) {
    float lg = logits[(size_t)t * E_ + e];
    float sig = 1.f / (1.f + __expf(-lg));
    s_sc[lt][e] = sig;
    sc[e] = sig + gb[e];
  }
  float gs[G_];
  #pragma unroll
  for (int g = 0; g < G_; ++g) {
    float a = sc[g * 4], b = sc[g * 4 + 1], c = sc[g * 4 + 2], d = sc[g * 4 + 3];
    float hi1 = fmaxf(a, b), lo1 = fminf(a, b);
    float hi2 = fmaxf(c, d), lo2 = fminf(c, d);
    float m1 = fmaxf(hi1, hi2);
    float m2 = (hi1 >= hi2) ? fmaxf(lo1, hi2) : fmaxf(lo2, hi1);
    gs[g] = m1 + m2;
  }
  unsigned gm = 0;
  #pragma unroll
  for (int r = 0; r < 4; ++r) {
    float bv = -1e30f; int bi = 0;
    #pragma unroll
    for (int g = 0; g < G_; ++g)
      if (!(gm & (1u << g)) && gs[g] > bv) { bv = gs[g]; bi = g; }
    gm |= 1u << bi;
  }
  float msk[E_];
  #pragma unroll
  for (int e = 0; e < E_; ++e)
    msk[e] = ((gm >> (e >> 2)) & 1u) ? sc[e] : 0.f;
  unsigned um = 0; float wsum = 0.f;
  int idxs[8]; float wts[8];
  #pragma unroll
  for (int r = 0; r < 8; ++r) {
    float bv = -1e30f; int bi = 0;
    #pragma unroll
    for (int e = 0; e < E_; ++e)
      if (!(um & (1u << e)) && msk[e] > bv) { bv = msk[e]; bi = e; }
    um |= 1u << bi;
    idxs[r] = bi;
    float wv = s_sc[lt][bi];
    wts[r] = wv; wsum += wv;
  }
  float inv = SCALE_ / (wsum + 1e-20f);
  #pragma unroll
  for (int r = 0; r < 8; ++r) {
    idx8[(size_t)t * 8 + r] = idxs[r];
    wt8[(size_t)t * 8 + r] = wts[r] * inv;
    atomicAdd(&counts[idxs[r]], 1);
  }
}

// ---------------- scan (pad to 64) ----------------
__global__ void scan_kernel(const int* __restrict__ counts, int* __restrict__ offs) {
  if (threadIdx.x == 0 && blockIdx.x == 0) {
    int run = 0;
    for (int e = 0; e < E_; ++e) {
      offs[e] = run;
      run += ((counts[e] + 63) >> 6) << 6;
    }
    offs[E_] = run;
  }
}

// ---------------- fill ----------------
__global__ void fill_kernel(const int* __restrict__ idx8, const float* __restrict__ wt8,
                            const int* __restrict__ offs, int* __restrict__ cursor,
                            int* __restrict__ tok_list, float* __restrict__ wt_list,
                            int* __restrict__ pair_pos, int npair) {
  int i = blockIdx.x * blockDim.x + threadIdx.x;
  if (i >= npair) return;
  int e = idx8[i];
  int p = atomicAdd(&cursor[e], 1);
  int slot = offs[e] + p;
  tok_list[slot] = i >> 3;
  wt_list[slot] = wt8[i];
  pair_pos[i] = slot;
}

// ---------------- phase 1: gathered dual GEMM ----------------
// 256 thr = 4 waves (2x2). Tile 64 tok x 64 cols (dual). LDS 24KB -> 6 blk/CU.
__global__ __launch_bounds__(256, 6) void p1_kernel(
    const u16* __restrict__ hbf,
    const u16* __restrict__ bg, const u16* __restrict__ bu,
    const u16* __restrict__ bshg, const u16* __restrict__ bshu,
    const int* __restrict__ counts, const int* __restrict__ offs,
    const int* __restrict__ tok_list, const float* __restrict__ wt_list,
    u16* __restrict__ gu,          // [PADCAP][512]
    u16* __restrict__ gu_sh,       // [T][1024]
    int T) {
  const int z = blockIdx.z, tt = blockIdx.y, nb = blockIdx.x;
  const bool sh_e = (z == E_);
  if (!sh_e && nb >= 8) return;
  const int cnt = sh_e ? T : counts[z];
  if (tt * 64 >= cnt) return;
  const int off = sh_e ? 0 : offs[z];

  __shared__ u16 lsA[64 * 64];
  __shared__ u16 lsB0[64 * 64];
  __shared__ u16 lsB1[64 * 64];
  __shared__ int s_tok[64];
  __shared__ float s_wt[64];

  const int tid = threadIdx.x;
  if (tid < 64) {
    if (sh_e) { s_tok[tid] = tt * 64 + tid; s_wt[tid] = 1.0f; }
    else {
      int slot = off + tt * 64 + tid;
      s_tok[tid] = tok_list[slot];
      s_wt[tid] = wt_list[slot];
    }
  }
  __syncthreads();

  const u16* Bg = sh_e ? (bshg + (size_t)(nb * 64) * H_)
                       : (bg + ((size_t)z * I_ + nb * 64) * H_);
  const u16* Bu = sh_e ? (bshu + (size_t)(nb * 64) * H_)
                       : (bu + ((size_t)z * I_ + nb * 64) * H_);

  const int w = tid >> 6, l = tid & 63;
  const int wr = w >> 1, wc = w & 1;
  const int lr = l & 15, lh = l >> 4;

  f32x4_t acc0[2][2], acc1[2][2];
  #pragma unroll
  for (int m = 0; m < 2; ++m)
    #pragma unroll
    for (int n = 0; n < 2; ++n) {
      acc0[m][n] = (f32x4_t){0.f, 0.f, 0.f, 0.f};
      acc1[m][n] = (f32x4_t){0.f, 0.f, 0.f, 0.f};
    }

  for (int k0 = 0; k0 < H_; k0 += 64) {
    #pragma unroll
    for (int i = 0; i < 2; ++i) {
      int c = tid + 256 * i;
      int row = c >> 3, cb = c & 7;
      load_lds16(hbf + (size_t)s_tok[row] * H_ + k0 + cb * 8, (char*)lsA + c * 16);
      load_lds16(Bg + (size_t)row * H_ + k0 + cb * 8, (char*)lsB0 + c * 16);
      load_lds16(Bu + (size_t)row * H_ + k0 + cb * 8, (char*)lsB1 + c * 16);
    }
    __syncthreads();
    #pragma unroll
    for (int kk = 0; kk < 64; kk += 32) {
      bf16x8_t af[2], b0f[2], b1f[2];
      #pragma unroll
      for (int m = 0; m < 2; ++m)
        af[m] = *(const bf16x8_t*)(lsA + (wr * 32 + m * 16 + lr) * 64 + kk + lh * 8);
      #pragma unroll
      for (int n = 0; n < 2; ++n) {
        b0f[n] = *(const bf16x8_t*)(lsB0 + (wc * 32 + n * 16 + lr) * 64 + kk + lh * 8);
        b1f[n] = *(const bf16x8_t*)(lsB1 + (wc * 32 + n * 16 + lr) * 64 + kk + lh * 8);
      }
      #pragma unroll
      for (int m = 0; m < 2; ++m)
        #pragma unroll
        for (int n = 0; n < 2; ++n) {
          acc0[m][n] = __builtin_amdgcn_mfma_f32_16x16x32_bf16(af[m], b0f[n], acc0[m][n], 0, 0, 0);
          acc1[m][n] = __builtin_amdgcn_mfma_f32_16x16x32_bf16(af[m], b1f[n], acc1[m][n], 0, 0, 0);
        }
    }
    __syncthreads();
  }

  const int ldo = sh_e ? (I_ * NSH_) : I_;
  u16* outp = sh_e ? (gu_sh + (size_t)(tt * 64) * ldo + nb * 64)
                   : (gu + (size_t)(off + tt * 64) * ldo + nb * 64);
  #pragma unroll
  for (int m = 0; m < 2; ++m) {
    #pragma unroll
    for (int n = 0; n < 2; ++n) {
      int col = wc * 32 + n * 16 + lr;
      #pragma unroll
      for (int j = 0; j < 4; ++j) {
        int trow = wr * 32 + m * 16 + lh * 4 + j;
        float gv = acc0[m][n][j], uv = acc1[m][n][j];
        float sv = gv / (1.f + __expf(-gv));
        outp[(size_t)trow * ldo + col] = f2bf(sv * uv * s_wt[trow]);
      }
    }
  }
}

// ---------------- phase 2: gathered GEMM (down) ----------------
// 256 thr = 4 waves (2x2). Tile 64 pairs x 128 H-cols. LDS 24KB -> 6 blk/CU.
__global__ __launch_bounds__(256, 6) void p2_kernel(
    const u16* __restrict__ gu, const u16* __restrict__ gu_sh,
    const u16* __restrict__ bd,    // [E][H][I] bf16
    const u16* __restrict__ bshd,  // [H][2I] bf16
    const int* __restrict__ counts, const int* __restrict__ offs,
    u16* __restrict__ part,        // [PADCAP][H]
    u16* __restrict__ part_sh,     // [T][H]
    int T) {
  const int z = blockIdx.z, tt = blockIdx.y, nb = blockIdx.x;
  const bool sh_e = (z == E_);
  const int cnt = sh_e ? T : counts[z];
  if (tt * 64 >= cnt) return;

  __shared__ u16 lsA[64 * 64];
  __shared__ u16 lsB[128 * 64];

  const int tid = threadIdx.x;
  const int w = tid >> 6, l = tid & 63;
  const int wr = w >> 1, wc = w & 1;
  const int lr = l & 15, lh = l >> 4;

  const int K = sh_e ? (I_ * NSH_) : I_;
  const int NT = K / 64;
  const u16* Ab = sh_e ? (gu_sh + (size_t)(tt * 64) * K)
                       : (gu + (size_t)(offs[z] + tt * 64) * K);
  const u16* Bb = sh_e ? (bshd + (size_t)(nb * 128) * K)
                       : (bd + (size_t)z * H_ * I_ + (size_t)(nb * 128) * K);
  u16* outp = sh_e ? (part_sh + (size_t)(tt * 64) * H_ + nb * 128)
                   : (part + (size_t)(offs[z] + tt * 64) * H_ + nb * 128);

  f32x4_t acc[2][4];
  #pragma unroll
  for (int m = 0; m < 2; ++m)
    #pragma unroll
    for (int n = 0; n < 4; ++n) acc[m][n] = (f32x4_t){0.f, 0.f, 0.f, 0.f};

  for (int s = 0; s < NT; ++s) {
    int k0 = s * 64;
    #pragma unroll
    for (int i = 0; i < 2; ++i) {
      int c = tid + 256 * i;
      int row = c >> 3, cb = c & 7;
      load_lds16(Ab + (size_t)row * K + k0 + cb * 8, (char*)lsA + c * 16);
    }
    #pragma unroll
    for (int i = 0; i < 4; ++i) {
      int c = tid + 256 * i;
      int row = c >> 3, cb = c & 7;
      load_lds16(Bb + (size_t)row * K + k0 + cb * 8, (char*)lsB + c * 16);
    }
    __syncthreads();
    #pragma unroll
    for (int kk = 0; kk < 64; kk += 32) {
      bf16x8_t af[2], bf[4];
      #pragma unroll
      for (int m = 0; m < 2; ++m)
        af[m] = *(const bf16x8_t*)(lsA + (wr * 32 + m * 16 + lr) * 64 + kk + lh * 8);
      #pragma unroll
      for (int n = 0; n < 4; ++n)
        bf[n] = *(const bf16x8_t*)(lsB + (wc * 64 + n * 16 + lr) * 64 + kk + lh * 8);
      #pragma unroll
      for (int m = 0; m < 2; ++m)
        #pragma unroll
        for (int n = 0; n < 4; ++n)
          acc[m][n] = __builtin_amdgcn_mfma_f32_16x16x32_bf16(af[m], bf[n], acc[m][n], 0, 0, 0);
    }
    __syncthreads();
  }

  #pragma unroll
  for (int m = 0; m < 2; ++m) {
    #pragma unroll
    for (int n = 0; n < 4; ++n) {
      int col = wc * 64 + n * 16 + lr;
      #pragma unroll
      for (int j = 0; j < 4; ++j) {
        int trow = wr * 32 + m * 16 + lh * 4 + j;
        outp[(size_t)trow * H_ + col] = f2bf(acc[m][n][j]);
      }
    }
  }
}

// ---------------- combine ----------------
__global__ void combine_kernel(const u16* __restrict__ part, const u16* __restrict__ part_sh,
                               const int* __restrict__ pair_pos, float* __restrict__ out) {
  int t = blockIdx.x;
  int h = threadIdx.x * 4;
  int pp[8];
  #pragma unroll
  for (int s = 0; s < 8; ++s) pp[s] = pair_pos[(long)t * 8 + s];
  ushort4 v = *(const ushort4*)(part_sh + (size_t)t * H_ + h);
  float a0 = bf2f(v.x), a1 = bf2f(v.y), a2 = bf2f(v.z), a3 = bf2f(v.w);
  #pragma unroll
  for (int s = 0; s < 8; ++s) {
    ushort4 u = *(const ushort4*)(part + (size_t)pp[s] * H_ + h);
    a0 += bf2f(u.x); a1 += bf2f(u.y); a2 += bf2f(u.z); a3 += bf2f(u.w);
  }
  float4 o = {a0, a1, a2, a3};
  *(float4*)(out + (size_t)t * H_ + h) = o;
}

extern "C" void kernel_launch(void* const* d_in, const int* in_sizes, int n_in,
                              void* d_out, int out_size, void* d_ws, size_t ws_size,
                              hipStream_t stream) {
  const float* hs  = (const float*)d_in[0];
  const float* gw  = (const float*)d_in[1];
  const float* gb  = (const float*)d_in[2];
  const float* wg  = (const float*)d_in[3];
  const float* wu  = (const float*)d_in[4];
  const float* wd  = (const float*)d_in[5];
  const float* shg = (const float*)d_in[6];
  const float* shu = (const float*)d_in[7];
  const float* shd = (const float*)d_in[8];
  float* out = (float*)d_out;

  const int T = in_sizes[0] / H_;  // 2048

  char* ws = (char*)d_ws;
  size_t off = 0;
  auto alloc = [&](size_t bytes) {
    char* p = ws + off;
    off += (bytes + 255) & ~(size_t)255;
    return p;
  };
  int*   counts   = (int*)alloc(E_ * 4);
  int*   cursor   = (int*)alloc(E_ * 4);
  int*   offsv    = (int*)alloc((E_ + 1) * 4);
  int*   idx8     = (int*)alloc((size_t)T * 8 * 4);
  float* wt8      = (float*)alloc((size_t)T * 8 * 4);
  int*   pair_pos = (int*)alloc((size_t)T * 8 * 4);
  int*   tok_list = (int*)alloc(PADCAP * 4);
  float* wt_list  = (float*)alloc(PADCAP * 4);
  float* gwT      = (float*)alloc((size_t)H_ * E_ * 4);
  float* logits   = (float*)alloc((size_t)T * E_ * 4);
  u16* hbf     = (u16*)alloc((size_t)T * H_ * 2);
  u16* wbf     = (u16*)alloc((size_t)W4_TOT * 4 * 2);  // all weights bf16
  u16* gu      = (u16*)alloc((size_t)PADCAP * I_ * 2);
  u16* gu_sh   = (u16*)alloc((size_t)T * I_ * NSH_ * 2);
  u16* part    = (u16*)alloc((size_t)PADCAP * H_ * 2);
  u16* part_sh = (u16*)alloc((size_t)T * H_ * 2);
  if (off > ws_size) return;

  u16* bg   = wbf;
  u16* bu   = wbf + (size_t)NROUTED * H_;
  u16* bd   = bu + (size_t)NROUTED * H_;
  u16* bshg = bd + (size_t)E_ * H_ * I_;
  u16* bshu = bshg + (size_t)I_ * NSH_ * H_;
  u16* bshd = bshu + (size_t)I_ * NSH_ * H_;

  hipLaunchKernelGGL(init_kernel, dim3((PADCAP + 255) / 256), dim3(256), 0, stream,
                     counts, cursor, tok_list, wt_list);

  // router (f32 exact)
  hipLaunchKernelGGL(gwt_kernel, dim3((H_ * E_ + 255) / 256), dim3(256), 0, stream, gw, gwT);
  hipLaunchKernelGGL(logits_kernel, dim3(T / 8), dim3(256), 0, stream, hs, gwT, logits);
  hipLaunchKernelGGL(topk_kernel, dim3(T / 256), dim3(256), 0, stream,
                     logits, gb, idx8, wt8, counts);
  hipLaunchKernelGGL(scan_kernel, dim3(1), dim3(64), 0, stream, counts, offsv);
  hipLaunchKernelGGL(fill_kernel, dim3((T * 8 + 255) / 256), dim3(256), 0, stream,
                     idx8, wt8, offsv, cursor, tok_list, wt_list, pair_pos, T * 8);

  // conversions
  {
    long n4 = (long)T * H_ / 4;
    hipLaunchKernelGGL(cvt_kernel, dim3((int)((n4 + 255) / 256)), dim3(256), 0, stream,
                       hs, hbf, n4);
  }
  hipLaunchKernelGGL(cvtw_kernel, dim3(2048), dim3(256), 0, stream,
                     wg, wu, wd, shg, shu, shd, wbf);

  hipLaunchKernelGGL(p1_kernel, dim3(16, T / 64, E_ + 1), dim3(256), 0, stream,
                     hbf, bg, bu, bshg, bshu, counts, offsv, tok_list, wt_list,
                     gu, gu_sh, T);

  hipLaunchKernelGGL(p2_kernel, dim3(8, T / 64, E_ + 1), dim3(256), 0, stream,
                     gu, gu_sh, bd, bshd, counts, offsv, part, part_sh, T);

  hipLaunchKernelGGL(combine_kernel, dim3(T), dim3(256), 0, stream,
                     part, part_sh, pair_pos, out);
}

// Round 6
// 312.403 us; speedup vs baseline: 1.6213x; 1.1596x over previous
//
#include <hip/hip_runtime.h>
#include <hip/hip_bf16.h>
#include <cstdint>

#define E_ 32
#define H_ 1024
#define I_ 512
#define G_ 8
#define NSH_ 2
#define SCALE_ 2.5f
#define NROUTED (E_ * I_)            // 16384
#define PADCAP (16384 + E_ * 128)    // 20480, pad-to-128

typedef unsigned short u16;
using bf16x8_t = __attribute__((ext_vector_type(8))) __bf16;
using f32x4_t  = __attribute__((ext_vector_type(4))) float;

__device__ __forceinline__ u16 f2bf(float x) {
  union { float f; uint32_t u; } v; v.f = x;
  uint32_t u = v.u;
  uint32_t r = (u + 0x7fffu + ((u >> 16) & 1u)) >> 16;
  return (u16)r;
}
__device__ __forceinline__ float bf2f(u16 x) {
  union { uint32_t u; float f; } v; v.u = ((uint32_t)x) << 16; return v.f;
}

__device__ __forceinline__ void load_lds16(const void* g, void* l) {
  __builtin_amdgcn_global_load_lds(
      (const __attribute__((address_space(1))) unsigned int*)g,
      (__attribute__((address_space(3))) unsigned int*)l,
      16, 0, 0);
}

// ---------------- hs f32 -> bf16 ----------------
__global__ void cvt_kernel(const float* __restrict__ src, u16* __restrict__ dst, long n4) {
  long i = (long)blockIdx.x * blockDim.x + threadIdx.x;
  if (i >= n4) return;
  float4 v = ((const float4*)src)[i];
  ushort4 o;
  o.x = f2bf(v.x); o.y = f2bf(v.y); o.z = f2bf(v.z); o.w = f2bf(v.w);
  ((ushort4*)dst)[i] = o;
}

// ---------------- all weights f32 -> bf16, one grid-stride kernel ----------
#define W4_WG  4194304L
#define W4_WU  8388608L
#define W4_WD  12582912L
#define W4_SHG 12845056L
#define W4_SHU 13107200L
#define W4_TOT 13369344L
__global__ void cvtw_kernel(const float* __restrict__ wg, const float* __restrict__ wu,
                            const float* __restrict__ wd, const float* __restrict__ shg,
                            const float* __restrict__ shu, const float* __restrict__ shd,
                            u16* __restrict__ dst) {
  long i = (long)blockIdx.x * blockDim.x + threadIdx.x;
  long stride = (long)gridDim.x * blockDim.x;
  for (; i < W4_TOT; i += stride) {
    const float* s; long off;
    if (i < W4_WG)       { s = wg;  off = i; }
    else if (i < W4_WU)  { s = wu;  off = i - W4_WG; }
    else if (i < W4_WD)  { s = wd;  off = i - W4_WU; }
    else if (i < W4_SHG) { s = shg; off = i - W4_WD; }
    else if (i < W4_SHU) { s = shu; off = i - W4_SHG; }
    else                 { s = shd; off = i - W4_SHU; }
    float4 v = ((const float4*)s)[off];
    ushort4 o;
    o.x = f2bf(v.x); o.y = f2bf(v.y); o.z = f2bf(v.z); o.w = f2bf(v.w);
    ((ushort4*)dst)[i] = o;
  }
}

// ---------------- init ----------------
__global__ void init_kernel(int* __restrict__ counts, int* __restrict__ cursor,
                            int* __restrict__ tok_list, float* __restrict__ wt_list) {
  int i = blockIdx.x * blockDim.x + threadIdx.x;
  if (i < PADCAP) { tok_list[i] = 0; wt_list[i] = 0.f; }
  if (i < E_) { counts[i] = 0; cursor[i] = 0; }
}

// ---------------- router a: gw [E][H] -> gwT [H][E] ----------------
__global__ void gwt_kernel(const float* __restrict__ gw, float* __restrict__ gwT) {
  int i = blockIdx.x * blockDim.x + threadIdx.x;
  if (i >= H_ * E_) return;
  int k = i >> 5, e = i & 31;
  gwT[i] = gw[(long)e * H_ + k];
}

// ---------------- router b: logits (f32 exact) ----------
__global__ __launch_bounds__(256) void logits_kernel(
    const float* __restrict__ h, const float* __restrict__ gwT,
    float* __restrict__ logits) {
  __shared__ float sh[8][H_];
  const int tid = threadIdx.x;
  const int t0 = blockIdx.x * 8;
  #pragma unroll
  for (int c = tid; c < 8 * H_ / 4; c += 256) {
    int row = c / (H_ / 4), col = c % (H_ / 4);
    ((float4*)sh[row])[col] = ((const float4*)(h + (size_t)(t0 + row) * H_))[col];
  }
  __syncthreads();
  const int w = tid >> 6, l = tid & 63;
  const int e = l & 31, tl = w * 2 + (l >> 5);
  const float* hp = sh[tl];
  const float* wp = gwT + e;
  float acc = 0.f;
  #pragma unroll 8
  for (int k = 0; k < H_; ++k) acc += hp[k] * wp[(size_t)k * E_];
  logits[(size_t)(t0 + tl) * E_ + e] = acc;
}

// ---------------- router c: top-k (1 thread / token) ----------------
__global__ __launch_bounds__(256) void topk_kernel(
    const float* __restrict__ logits, const float* __restrict__ gb,
    int* __restrict__ idx8, float* __restrict__ wt8, int* __restrict__ counts) {
  __shared__ float s_sc[256][33];
  const int lt = threadIdx.x;
  const int t = blockIdx.x * 256 + lt;
  float sc[E_];
  #pragma unroll
  for (int e = 0; e < E_; ++e) {
    float lg = logits[(size_t)t * E_ + e];
    float sig = 1.f / (1.f + __expf(-lg));
    s_sc[lt][e] = sig;
    sc[e] = sig + gb[e];
  }
  float gs[G_];
  #pragma unroll
  for (int g = 0; g < G_; ++g) {
    float a = sc[g * 4], b = sc[g * 4 + 1], c = sc[g * 4 + 2], d = sc[g * 4 + 3];
    float hi1 = fmaxf(a, b), lo1 = fminf(a, b);
    float hi2 = fmaxf(c, d), lo2 = fminf(c, d);
    float m1 = fmaxf(hi1, hi2);
    float m2 = (hi1 >= hi2) ? fmaxf(lo1, hi2) : fmaxf(lo2, hi1);
    gs[g] = m1 + m2;
  }
  unsigned gm = 0;
  #pragma unroll
  for (int r = 0; r < 4; ++r) {
    float bv = -1e30f; int bi = 0;
    #pragma unroll
    for (int g = 0; g < G_; ++g)
      if (!(gm & (1u << g)) && gs[g] > bv) { bv = gs[g]; bi = g; }
    gm |= 1u << bi;
  }
  float msk[E_];
  #pragma unroll
  for (int e = 0; e < E_; ++e)
    msk[e] = ((gm >> (e >> 2)) & 1u) ? sc[e] : 0.f;
  unsigned um = 0; float wsum = 0.f;
  int idxs[8]; float wts[8];
  #pragma unroll
  for (int r = 0; r < 8; ++r) {
    float bv = -1e30f; int bi = 0;
    #pragma unroll
    for (int e = 0; e < E_; ++e)
      if (!(um & (1u << e)) && msk[e] > bv) { bv = msk[e]; bi = e; }
    um |= 1u << bi;
    idxs[r] = bi;
    float wv = s_sc[lt][bi];
    wts[r] = wv; wsum += wv;
  }
  float inv = SCALE_ / (wsum + 1e-20f);
  #pragma unroll
  for (int r = 0; r < 8; ++r) {
    idx8[(size_t)t * 8 + r] = idxs[r];
    wt8[(size_t)t * 8 + r] = wts[r] * inv;
    atomicAdd(&counts[idxs[r]], 1);
  }
}

// ---------------- scan (pad to 128) ----------------
__global__ void scan_kernel(const int* __restrict__ counts, int* __restrict__ offs) {
  if (threadIdx.x == 0 && blockIdx.x == 0) {
    int run = 0;
    for (int e = 0; e < E_; ++e) {
      offs[e] = run;
      run += ((counts[e] + 127) >> 7) << 7;
    }
    offs[E_] = run;
  }
}

// ---------------- fill ----------------
__global__ void fill_kernel(const int* __restrict__ idx8, const float* __restrict__ wt8,
                            const int* __restrict__ offs, int* __restrict__ cursor,
                            int* __restrict__ tok_list, float* __restrict__ wt_list,
                            int* __restrict__ pair_pos, int npair) {
  int i = blockIdx.x * blockDim.x + threadIdx.x;
  if (i >= npair) return;
  int e = idx8[i];
  int p = atomicAdd(&cursor[e], 1);
  int slot = offs[e] + p;
  tok_list[slot] = i >> 3;
  wt_list[slot] = wt8[i];
  pair_pos[i] = slot;
}

// ---------------- phase 1: gathered dual GEMM, swizzled LDS ----------------
// 256 thr = 4 waves (2x2). Tile 128 tok x 64 cols (dual gate+up).
// LDS tiles [rows][64] u16; 16B-block cb holds global block cb^(row&7).
__global__ __launch_bounds__(256, 4) void p1_kernel(
    const u16* __restrict__ hbf,
    const u16* __restrict__ bg, const u16* __restrict__ bu,
    const u16* __restrict__ bshg, const u16* __restrict__ bshu,
    const int* __restrict__ counts, const int* __restrict__ offs,
    const int* __restrict__ tok_list, const float* __restrict__ wt_list,
    u16* __restrict__ gu,          // [PADCAP][512]
    u16* __restrict__ gu_sh,       // [T][1024]
    int T) {
  const int z = blockIdx.z, tt = blockIdx.y, nb = blockIdx.x;
  const bool sh_e = (z == E_);
  if (!sh_e && nb >= 8) return;
  const int cnt = sh_e ? T : counts[z];
  if (tt * 128 >= cnt) return;
  const int off = sh_e ? 0 : offs[z];

  __shared__ u16 lsA[128 * 64];
  __shared__ u16 lsB0[64 * 64];
  __shared__ u16 lsB1[64 * 64];
  __shared__ int s_tok[128];
  __shared__ float s_wt[128];

  const int tid = threadIdx.x;
  if (tid < 128) {
    if (sh_e) { s_tok[tid] = tt * 128 + tid; s_wt[tid] = 1.0f; }
    else {
      int slot = off + tt * 128 + tid;
      s_tok[tid] = tok_list[slot];
      s_wt[tid] = wt_list[slot];
    }
  }
  __syncthreads();

  const u16* Bg = sh_e ? (bshg + (size_t)(nb * 64) * H_)
                       : (bg + ((size_t)z * I_ + nb * 64) * H_);
  const u16* Bu = sh_e ? (bshu + (size_t)(nb * 64) * H_)
                       : (bu + ((size_t)z * I_ + nb * 64) * H_);

  const int w = tid >> 6, l = tid & 63;
  const int wr = w >> 1, wc = w & 1;
  const int lr = l & 15, lh = l >> 4;
  const int sw = lr & 7;   // per-lane read swizzle

  f32x4_t acc0[4][2], acc1[4][2];
  #pragma unroll
  for (int m = 0; m < 4; ++m)
    #pragma unroll
    for (int n = 0; n < 2; ++n) {
      acc0[m][n] = (f32x4_t){0.f, 0.f, 0.f, 0.f};
      acc1[m][n] = (f32x4_t){0.f, 0.f, 0.f, 0.f};
    }

  for (int k0 = 0; k0 < H_; k0 += 64) {
    // A: 128 rows x 8 blocks = 1024 chunks
    #pragma unroll
    for (int i = 0; i < 4; ++i) {
      int c = tid + 256 * i;
      int row = c >> 3, cb = c & 7;
      int scb = cb ^ (row & 7);
      load_lds16(hbf + (size_t)s_tok[row] * H_ + k0 + scb * 8, (char*)lsA + c * 16);
    }
    // B0/B1: 64 rows x 8 blocks = 512 chunks each
    #pragma unroll
    for (int i = 0; i < 2; ++i) {
      int c = tid + 256 * i;
      int row = c >> 3, cb = c & 7;
      int scb = cb ^ (row & 7);
      load_lds16(Bg + (size_t)row * H_ + k0 + scb * 8, (char*)lsB0 + c * 16);
      load_lds16(Bu + (size_t)row * H_ + k0 + scb * 8, (char*)lsB1 + c * 16);
    }
    __syncthreads();
    #pragma unroll
    for (int kk = 0; kk < 64; kk += 32) {
      const int sb = kk >> 3;            // 0 or 4
      const int blk = ((sb + lh) ^ sw) << 3;
      bf16x8_t af[4], b0f[2], b1f[2];
      #pragma unroll
      for (int m = 0; m < 4; ++m)
        af[m] = *(const bf16x8_t*)(lsA + (wr * 64 + m * 16 + lr) * 64 + blk);
      #pragma unroll
      for (int n = 0; n < 2; ++n) {
        b0f[n] = *(const bf16x8_t*)(lsB0 + (wc * 32 + n * 16 + lr) * 64 + blk);
        b1f[n] = *(const bf16x8_t*)(lsB1 + (wc * 32 + n * 16 + lr) * 64 + blk);
      }
      #pragma unroll
      for (int m = 0; m < 4; ++m)
        #pragma unroll
        for (int n = 0; n < 2; ++n) {
          acc0[m][n] = __builtin_amdgcn_mfma_f32_16x16x32_bf16(af[m], b0f[n], acc0[m][n], 0, 0, 0);
          acc1[m][n] = __builtin_amdgcn_mfma_f32_16x16x32_bf16(af[m], b1f[n], acc1[m][n], 0, 0, 0);
        }
    }
    __syncthreads();
  }

  const int ldo = sh_e ? (I_ * NSH_) : I_;
  u16* outp = sh_e ? (gu_sh + (size_t)(tt * 128) * ldo + nb * 64)
                   : (gu + (size_t)(off + tt * 128) * ldo + nb * 64);
  #pragma unroll
  for (int m = 0; m < 4; ++m) {
    #pragma unroll
    for (int n = 0; n < 2; ++n) {
      int col = wc * 32 + n * 16 + lr;
      #pragma unroll
      for (int j = 0; j < 4; ++j) {
        int trow = wr * 64 + m * 16 + lh * 4 + j;
        float gv = acc0[m][n][j], uv = acc1[m][n][j];
        float sv = gv / (1.f + __expf(-gv));
        outp[(size_t)trow * ldo + col] = f2bf(sv * uv * s_wt[trow]);
      }
    }
  }
}

// ---------------- phase 2: gathered GEMM (down), swizzled LDS ----------------
// 256 thr = 4 waves (2x2). Tile 128 pairs x 64 H-cols. K=512 routed / 1024 shared.
__global__ __launch_bounds__(256, 6) void p2_kernel(
    const u16* __restrict__ gu, const u16* __restrict__ gu_sh,
    const u16* __restrict__ bd,    // [E][H][I] bf16
    const u16* __restrict__ bshd,  // [H][2I] bf16
    const int* __restrict__ counts, const int* __restrict__ offs,
    u16* __restrict__ part,        // [PADCAP][H]
    u16* __restrict__ part_sh,     // [T][H]
    int T) {
  const int z = blockIdx.z, tt = blockIdx.y, nb = blockIdx.x;  // nb: 16 x 64-col
  const bool sh_e = (z == E_);
  const int cnt = sh_e ? T : counts[z];
  if (tt * 128 >= cnt) return;

  __shared__ u16 lsA[128 * 64];
  __shared__ u16 lsB[64 * 64];

  const int tid = threadIdx.x;
  const int w = tid >> 6, l = tid & 63;
  const int wr = w >> 1, wc = w & 1;
  const int lr = l & 15, lh = l >> 4;
  const int sw = lr & 7;

  const int K = sh_e ? (I_ * NSH_) : I_;
  const int NT = K / 64;
  const u16* Ab = sh_e ? (gu_sh + (size_t)(tt * 128) * K)
                       : (gu + (size_t)(offs[z] + tt * 128) * K);
  const u16* Bb = sh_e ? (bshd + (size_t)(nb * 64) * K)
                       : (bd + (size_t)z * H_ * I_ + (size_t)(nb * 64) * K);
  u16* outp = sh_e ? (part_sh + (size_t)(tt * 128) * H_ + nb * 64)
                   : (part + (size_t)(offs[z] + tt * 128) * H_ + nb * 64);

  f32x4_t acc[4][2];
  #pragma unroll
  for (int m = 0; m < 4; ++m)
    #pragma unroll
    for (int n = 0; n < 2; ++n) acc[m][n] = (f32x4_t){0.f, 0.f, 0.f, 0.f};

  for (int s = 0; s < NT; ++s) {
    int k0 = s * 64;
    #pragma unroll
    for (int i = 0; i < 4; ++i) {
      int c = tid + 256 * i;
      int row = c >> 3, cb = c & 7;
      int scb = cb ^ (row & 7);
      load_lds16(Ab + (size_t)row * K + k0 + scb * 8, (char*)lsA + c * 16);
    }
    #pragma unroll
    for (int i = 0; i < 2; ++i) {
      int c = tid + 256 * i;
      int row = c >> 3, cb = c & 7;
      int scb = cb ^ (row & 7);
      load_lds16(Bb + (size_t)row * K + k0 + scb * 8, (char*)lsB + c * 16);
    }
    __syncthreads();
    #pragma unroll
    for (int kk = 0; kk < 64; kk += 32) {
      const int sb = kk >> 3;
      const int blk = ((sb + lh) ^ sw) << 3;
      bf16x8_t af[4], bf[2];
      #pragma unroll
      for (int m = 0; m < 4; ++m)
        af[m] = *(const bf16x8_t*)(lsA + (wr * 64 + m * 16 + lr) * 64 + blk);
      #pragma unroll
      for (int n = 0; n < 2; ++n)
        bf[n] = *(const bf16x8_t*)(lsB + (wc * 32 + n * 16 + lr) * 64 + blk);
      #pragma unroll
      for (int m = 0; m < 4; ++m)
        #pragma unroll
        for (int n = 0; n < 2; ++n)
          acc[m][n] = __builtin_amdgcn_mfma_f32_16x16x32_bf16(af[m], bf[n], acc[m][n], 0, 0, 0);
    }
    __syncthreads();
  }

  #pragma unroll
  for (int m = 0; m < 4; ++m) {
    #pragma unroll
    for (int n = 0; n < 2; ++n) {
      int col = wc * 32 + n * 16 + lr;
      #pragma unroll
      for (int j = 0; j < 4; ++j) {
        int trow = wr * 64 + m * 16 + lh * 4 + j;
        outp[(size_t)trow * H_ + col] = f2bf(acc[m][n][j]);
      }
    }
  }
}

// ---------------- combine ----------------
__global__ void combine_kernel(const u16* __restrict__ part, const u16* __restrict__ part_sh,
                               const int* __restrict__ pair_pos, float* __restrict__ out) {
  int t = blockIdx.x;
  int h = threadIdx.x * 4;
  int pp[8];
  #pragma unroll
  for (int s = 0; s < 8; ++s) pp[s] = pair_pos[(long)t * 8 + s];
  ushort4 v = *(const ushort4*)(part_sh + (size_t)t * H_ + h);
  float a0 = bf2f(v.x), a1 = bf2f(v.y), a2 = bf2f(v.z), a3 = bf2f(v.w);
  #pragma unroll
  for (int s = 0; s < 8; ++s) {
    ushort4 u = *(const ushort4*)(part + (size_t)pp[s] * H_ + h);
    a0 += bf2f(u.x); a1 += bf2f(u.y); a2 += bf2f(u.z); a3 += bf2f(u.w);
  }
  float4 o = {a0, a1, a2, a3};
  *(float4*)(out + (size_t)t * H_ + h) = o;
}

extern "C" void kernel_launch(void* const* d_in, const int* in_sizes, int n_in,
                              void* d_out, int out_size, void* d_ws, size_t ws_size,
                              hipStream_t stream) {
  const float* hs  = (const float*)d_in[0];
  const float* gw  = (const float*)d_in[1];
  const float* gb  = (const float*)d_in[2];
  const float* wg  = (const float*)d_in[3];
  const float* wu  = (const float*)d_in[4];
  const float* wd  = (const float*)d_in[5];
  const float* shg = (const float*)d_in[6];
  const float* shu = (const float*)d_in[7];
  const float* shd = (const float*)d_in[8];
  float* out = (float*)d_out;

  const int T = in_sizes[0] / H_;  // 2048

  char* ws = (char*)d_ws;
  size_t off = 0;
  auto alloc = [&](size_t bytes) {
    char* p = ws + off;
    off += (bytes + 255) & ~(size_t)255;
    return p;
  };
  int*   counts   = (int*)alloc(E_ * 4);
  int*   cursor   = (int*)alloc(E_ * 4);
  int*   offsv    = (int*)alloc((E_ + 1) * 4);
  int*   idx8     = (int*)alloc((size_t)T * 8 * 4);
  float* wt8      = (float*)alloc((size_t)T * 8 * 4);
  int*   pair_pos = (int*)alloc((size_t)T * 8 * 4);
  int*   tok_list = (int*)alloc(PADCAP * 4);
  float* wt_list  = (float*)alloc(PADCAP * 4);
  float* gwT      = (float*)alloc((size_t)H_ * E_ * 4);
  float* logits   = (float*)alloc((size_t)T * E_ * 4);
  u16* hbf     = (u16*)alloc((size_t)T * H_ * 2);
  u16* wbf     = (u16*)alloc((size_t)W4_TOT * 4 * 2);
  u16* gu      = (u16*)alloc((size_t)PADCAP * I_ * 2);
  u16* gu_sh   = (u16*)alloc((size_t)T * I_ * NSH_ * 2);
  u16* part    = (u16*)alloc((size_t)PADCAP * H_ * 2);
  u16* part_sh = (u16*)alloc((size_t)T * H_ * 2);
  if (off > ws_size) return;

  u16* bg   = wbf;
  u16* bu   = wbf + (size_t)NROUTED * H_;
  u16* bd   = bu + (size_t)NROUTED * H_;
  u16* bshg = bd + (size_t)E_ * H_ * I_;
  u16* bshu = bshg + (size_t)I_ * NSH_ * H_;
  u16* bshd = bshu + (size_t)I_ * NSH_ * H_;

  hipLaunchKernelGGL(init_kernel, dim3((PADCAP + 255) / 256), dim3(256), 0, stream,
                     counts, cursor, tok_list, wt_list);

  // router (f32 exact)
  hipLaunchKernelGGL(gwt_kernel, dim3((H_ * E_ + 255) / 256), dim3(256), 0, stream, gw, gwT);
  hipLaunchKernelGGL(logits_kernel, dim3(T / 8), dim3(256), 0, stream, hs, gwT, logits);
  hipLaunchKernelGGL(topk_kernel, dim3(T / 256), dim3(256), 0, stream,
                     logits, gb, idx8, wt8, counts);
  hipLaunchKernelGGL(scan_kernel, dim3(1), dim3(64), 0, stream, counts, offsv);
  hipLaunchKernelGGL(fill_kernel, dim3((T * 8 + 255) / 256), dim3(256), 0, stream,
                     idx8, wt8, offsv, cursor, tok_list, wt_list, pair_pos, T * 8);

  // conversions
  {
    long n4 = (long)T * H_ / 4;
    hipLaunchKernelGGL(cvt_kernel, dim3((int)((n4 + 255) / 256)), dim3(256), 0, stream,
                       hs, hbf, n4);
  }
  hipLaunchKernelGGL(cvtw_kernel, dim3(2048), dim3(256), 0, stream,
                     wg, wu, wd, shg, shu, shd, wbf);

  hipLaunchKernelGGL(p1_kernel, dim3(16, T / 128, E_ + 1), dim3(256), 0, stream,
                     hbf, bg, bu, bshg, bshu, counts, offsv, tok_list, wt_list,
                     gu, gu_sh, T);

  hipLaunchKernelGGL(p2_kernel, dim3(16, T / 128, E_ + 1), dim3(256), 0, stream,
                     gu, gu_sh, bd, bshd, counts, offsv, part, part_sh, T);

  hipLaunchKernelGGL(combine_kernel, dim3(T), dim3(256), 0, stream,
                     part, part_sh, pair_pos, out);
}